// Round 10
// baseline (155.328 us; speedup 1.0000x reference)
//
#include <hip/hip_runtime.h>

#define NN 4096
#define DD 128
#define MMR 2048
#define KKE 1024
// fallback feat params (R5)
#define FJS 8
#define RB 16
#define JCH 128
#define NCH 4
#define FJS_TOT 32

typedef __attribute__((ext_vector_type(8))) short s16x8;
typedef __attribute__((ext_vector_type(4))) float f32x4;
typedef unsigned short u16;
typedef unsigned int u32;

#define SMALLV (-103.61632918439092f)
// exp(2*v - 4) == exp2(v*K1 + K2)
#define K1EXP 2.8853900817779268f
#define K2EXP (-5.7707801635558537f)

static __device__ __forceinline__ u16 f2bf(float x) {
    u32 u = __float_as_uint(x);
    u32 r = (u + 0x7fffu + ((u >> 16) & 1u)) >> 16;
    return (u16)r;
}
union HU { u16 u; _Float16 h; };
static __device__ __forceinline__ u16 f2h(float f) { HU x; x.h = (_Float16)f; return x.u; }
static __device__ __forceinline__ float h2f(u16 u) { HU x; x.u = u; return (float)x.h; }

static __device__ __forceinline__ f32x4 mfma_bf16(s16x8 a, s16x8 b, f32x4 c) {
    return __builtin_amdgcn_mfma_f32_16x16x32_bf16(a, b, c, 0, 0, 0);
}

static __device__ __forceinline__ void gload_lds16(const void* g, void* l) {
    __builtin_amdgcn_global_load_lds(
        (const __attribute__((address_space(1))) void*)g,
        (__attribute__((address_space(3))) void*)l, 16, 0, 0);
}

// ---------------- prep: all conversions in one launch ----------------
__global__ __launch_bounds__(256) void prep_all(
    const float* __restrict__ zi, const float* __restrict__ z,
    const float* __restrict__ real, const float* __restrict__ pseudo,
    const float* __restrict__ pseudos,
    u16* __restrict__ zin_bf, u16* __restrict__ zn_bf,
    u16* __restrict__ real_bf, u16* __restrict__ pseudo_bf,
    u16* __restrict__ pseudos_bf,
    float* __restrict__ nreal, float* __restrict__ npseudo,
    float* __restrict__ npseudos)
{
    int b = blockIdx.x;
    int sub = threadIdx.x >> 6, lane = threadIdx.x & 63;
    if (b < 2048) {
        int row = b * 4 + sub;   // 0..8191
        const float* src = (row < NN) ? zi : z;
        u16* dst = (row < NN) ? zin_bf : zn_bf;
        int r = (row < NN) ? row : row - NN;
        const float* p = src + (size_t)r * DD;
        float a = p[lane], c = p[lane + 64];
        float ss = a * a + c * c;
        #pragma unroll
        for (int d = 1; d < 64; d <<= 1) ss += __shfl_xor(ss, d);
        float nrm = fmaxf(sqrtf(ss), 1e-8f);
        dst[r * DD + lane]      = f2bf(a / nrm);
        dst[r * DD + lane + 64] = f2bf(c / nrm);
    } else {
        const float* src; u16* dst; float* sq; int r;
        if (b < 3072)      { r = (b - 2048) * 4 + sub; src = real;    dst = real_bf;    sq = nreal; }
        else if (b < 3584) { r = (b - 3072) * 4 + sub; src = pseudo;  dst = pseudo_bf;  sq = npseudo; }
        else               { r = (b - 3584) * 4 + sub; src = pseudos; dst = pseudos_bf; sq = npseudos; }
        const float* p = src + (size_t)r * DD;
        float a = p[lane], c = p[lane + 64];
        float ss = a * a + c * c;
        #pragma unroll
        for (int d = 1; d < 64; d <<= 1) ss += __shfl_xor(ss, d);
        if (lane == 0) sq[r] = ss;
        dst[r * DD + lane]      = f2bf(a);
        dst[r * DD + lane + 64] = f2bf(c);
    }
}

// ---------------- gram: materialize cross & inter as f16 ----------------
__global__ __launch_bounds__(256) void gram_kernel(
    const u16* __restrict__ zin, const u16* __restrict__ zn,
    u16* __restrict__ gc, u16* __restrict__ gi, int row0, int tile_rows)
{
    __shared__ u16 ldsc[128 * 136];
    int b = blockIdx.x;
    int per = tile_rows * 32;
    int mat = b / per;
    int loc = b % per;
    int ti = loc >> 5, tj = loc & 31;
    const short* A = (const short*)zin;
    const short* B = (const short*)(mat ? zin : zn);
    u16* dst = mat ? gi : gc;
    int wid = threadIdx.x >> 6, lane = threadIdx.x & 63;
    int lr = lane & 15, lg = lane >> 4;
    int Rb = row0 + ti * 128 + wid * 32;
    int Jb = tj * 128;
    f32x4 acc[2][8];
    f32x4 zz = {0.f, 0.f, 0.f, 0.f};
    #pragma unroll
    for (int rt = 0; rt < 2; ++rt)
        #pragma unroll
        for (int ct = 0; ct < 8; ++ct) acc[rt][ct] = zz;
    #pragma unroll
    for (int kk = 0; kk < 4; ++kk) {
        s16x8 a0 = *(const s16x8*)(A + (size_t)(Rb + lr) * DD + kk * 32 + lg * 8);
        s16x8 a1 = *(const s16x8*)(A + (size_t)(Rb + 16 + lr) * DD + kk * 32 + lg * 8);
        #pragma unroll
        for (int ct = 0; ct < 8; ++ct) {
            s16x8 bb = *(const s16x8*)(B + (size_t)(Jb + ct * 16 + lr) * DD + kk * 32 + lg * 8);
            acc[0][ct] = mfma_bf16(a0, bb, acc[0][ct]);
            acc[1][ct] = mfma_bf16(a1, bb, acc[1][ct]);
        }
    }
    #pragma unroll
    for (int rt = 0; rt < 2; ++rt)
        #pragma unroll
        for (int ct = 0; ct < 8; ++ct)
            #pragma unroll
            for (int r = 0; r < 4; ++r)
                ldsc[(wid * 32 + rt * 16 + lg * 4 + r) * 136 + ct * 16 + lr] =
                    f2h(acc[rt][ct][r]);
    __syncthreads();
    int row = threadIdx.x >> 1, half = threadIdx.x & 1;
    size_t gbase = (size_t)(ti * 128 + row) * NN + Jb + half * 64;
    #pragma unroll
    for (int i = 0; i < 8; ++i)
        *(s16x8*)(dst + gbase + i * 8) =
            *(const s16x8*)(&ldsc[row * 136 + half * 64 + i * 8]);
}

// ---------------- feat streaming pass: chip-coherent marching window ----------------
// 2048 blocks. Block b, iter k processes the 1024 contiguous elements at
// flat offset k*2097152 + b*1024 (one quarter-row). At any instant all 2048
// resident blocks cover ONE contiguous 8MB (fp32) / 4MB (f16) window per
// array -- the copy-bench access pattern. Per-iter: wave shfl reduce ->
// srow_part[row][(b&3)*4+wid] (deterministic, no atomics, no barriers).
__global__ __launch_bounds__(256) void feat_stream(
    const float* __restrict__ y_pse, const float* __restrict__ negw,
    const int* __restrict__ w,
    const u16* __restrict__ gc, const u16* __restrict__ gi,
    int row0, int kmax,
    float* __restrict__ srow_part, float* __restrict__ pos_part, int pass)
{
    int b = blockIdx.x, t = threadIdx.x;
    int wid = t >> 6, lane = t & 63;
    float pos = 0.0f;
    for (int k = 0; k < kmax; ++k) {
        int row_l = k * 512 + (b >> 2);
        int R = row0 + row_l;
        int col = (b & 3) * 1024 + t * 4;
        float4  y4 = *(const float4*)(y_pse + (size_t)R * NN + col);
        float4  n4 = *(const float4*)(negw  + (size_t)R * NN + col);
        int4    w4 = *(const int4*)(w       + (size_t)R * NN + col);
        ushort4 c4 = *(const ushort4*)(gc + (size_t)row_l * NN + col);
        ushort4 i4 = *(const ushort4*)(gi + (size_t)row_l * NN + col);
        float ya[4] = {y4.x, y4.y, y4.z, y4.w};
        float na[4] = {n4.x, n4.y, n4.z, n4.w};
        int   wa[4] = {w4.x, w4.y, w4.z, w4.w};
        u16   ca[4] = {c4.x, c4.y, c4.z, c4.w};
        u16   ia[4] = {i4.x, i4.y, i4.z, i4.w};
        float s0 = 0.0f;
        #pragma unroll
        for (int r = 0; r < 4; ++r) {
            int J = col + r;
            float y = ya[r];
            bool wm = (wa[r] != 0) || (R == J);
            float cross = 2.0f * h2f(ca[r]);   // cos / TEMP
            float inter = 2.0f * h2f(ia[r]);
            if (wm && (y > 0.0f)) pos += y * cross;
            bool nm = (!wm) && (y == 0.0f);
            float nwc = fmaxf(na[r], 0.0f);
            float vc = nm ? nwc * cross : 0.0f;
            vc = (vc == 0.0f) ? SMALLV : vc;
            float vi = nm ? nwc * inter : 0.0f;
            vi = (vi == 0.0f) ? SMALLV : vi;
            s0 += exp2f(fmaf(vc, K1EXP, K2EXP)) + exp2f(fmaf(vi, K1EXP, K2EXP));
        }
        // wave reduce; 16 partials per row: (b&3)*4 + wid
        #pragma unroll
        for (int d = 1; d < 64; d <<= 1) s0 += __shfl_xor(s0, d);
        if (lane == 0) srow_part[(size_t)R * 16 + (b & 3) * 4 + wid] = s0;
    }
    // pos: one block reduce at the very end
    #pragma unroll
    for (int d = 1; d < 64; d <<= 1) pos += __shfl_xor(pos, d);
    __shared__ float red[4];
    if (lane == 0) red[wid] = pos;
    __syncthreads();
    if (t == 0) pos_part[pass * 2048 + b] = red[0] + red[1] + red[2] + red[3];
}

// ---------------- per-row LSE finish (streaming path) ----------------
__global__ __launch_bounds__(256) void lse_stream_kernel(
    const float* __restrict__ srow_part, float* __restrict__ lse_part)
{
    int R = blockIdx.x * 256 + threadIdx.x;
    float s = 0.0f;
    #pragma unroll
    for (int k = 0; k < 16; ++k) s += srow_part[(size_t)R * 16 + k];
    float v = 4.0f + __logf(s);   // fixed-max LSE: max = 4
    #pragma unroll
    for (int d = 1; d < 64; d <<= 1) v += __shfl_xor(v, d);
    __shared__ float l[4];
    if ((threadIdx.x & 63) == 0) l[threadIdx.x >> 6] = v;
    __syncthreads();
    if (threadIdx.x == 0) lse_part[blockIdx.x] = l[0] + l[1] + l[2] + l[3];
}

// ---------------- final (streaming path) ----------------
__global__ __launch_bounds__(256) void final3_kernel(
    const float* __restrict__ lse_part, const float* __restrict__ pos_part,
    int npos_rounds, const float* __restrict__ partials, float* __restrict__ out)
{
    int t = threadIdx.x;
    float lse = (t < 16) ? lse_part[t] : 0.0f;
    float pos = 0.0f;
    for (int i = 0; i < npos_rounds; ++i) pos += pos_part[t + 256 * i];
    float xx = partials[t] + partials[t + 256];
    float yy = partials[512 + t];
    float xy = partials[768 + t];
    float pp = (t < 64) ? partials[1024 + t] : 0.0f;
    __shared__ float red[256];
    float vals[6] = {lse, pos, xx, yy, xy, pp};
    float tot[6];
    #pragma unroll
    for (int v = 0; v < 6; ++v) {
        red[t] = vals[v];
        __syncthreads();
        for (int d = 128; d > 0; d >>= 1) {
            if (t < d) red[t] += red[t + d];
            __syncthreads();
        }
        tot[v] = red[0];
        __syncthreads();
    }
    if (t == 0) {
        float feat = (tot[0] - tot[1]) / (float)NN;
        float sxx = tot[2] / ((float)NN * (NN - 1));
        float syy = tot[3] / ((float)MMR * (MMR - 1));
        float sxy = 2.0f * tot[4] / ((float)NN * MMR);
        out[0] = feat + sxx + syy - sxy + tot[5];
    }
}

// ================= R5 fallback feat path (only if ws too small) =================
__global__ __launch_bounds__(256) void feat_kernel(
    const u16* __restrict__ zin, const u16* __restrict__ zn,
    const float* __restrict__ y_pse, const float* __restrict__ negw,
    const int* __restrict__ w,
    float* __restrict__ row_s, float* __restrict__ pos_part)
{
    __shared__ char lds[2][3][8192];
    __shared__ float lds_pos[4];
    int js = blockIdx.x & (FJS - 1);
    int rb = blockIdx.x / FJS;
    int wid = threadIdx.x >> 6;
    int lane = threadIdx.x & 63;
    int lr = lane & 15, lg = lane >> 4;
    int R0 = rb * RB;
    int R = R0 + lr;
    int j00 = js * (NCH * JCH);
    const short* zin_s = (const short*)zin;
    const short* zn_s  = (const short*)zn;
    int half = lane >> 5, l32 = lane & 31;
    s16x8 bfrag[4];
    #pragma unroll
    for (int kk = 0; kk < 4; ++kk)
        bfrag[kk] = *(const s16x8*)(zin_s + (size_t)R * DD + kk * 32 + lg * 8);
    #define STAGE(c) do {                                                      \
        int j_ = j00 + (c) * JCH;                                              \
        char* Lb_ = &lds[(c) & 1][0][0];                                       \
        _Pragma("unroll")                                                      \
        for (int i_ = 0; i_ < 2; ++i_) {                                       \
            int k_ = wid * 2 + i_;                                             \
            int row_ = R0 + 2 * k_ + half;                                     \
            size_t eo_ = (size_t)row_ * NN + j_ + l32 * 4;                     \
            gload_lds16(y_pse + eo_, Lb_ + k_ * 1024);                         \
            gload_lds16(negw  + eo_, Lb_ + 8192 + k_ * 1024);                  \
            gload_lds16(w     + eo_, Lb_ + 16384 + k_ * 1024);                 \
        }                                                                      \
    } while (0)
    STAGE(0);
    float s0 = 0.0f, pos = 0.0f;
    #pragma unroll
    for (int c = 0; c < NCH; ++c) {
        s16x8 an[2][4], ai[2][4];
        #pragma unroll
        for (int t = 0; t < 2; ++t) {
            int jr = j00 + c * JCH + wid * 32 + t * 16 + lr;
            #pragma unroll
            for (int kk = 0; kk < 4; ++kk) {
                an[t][kk] = *(const s16x8*)(zn_s  + (size_t)jr * DD + kk * 32 + lg * 8);
                ai[t][kk] = *(const s16x8*)(zin_s + (size_t)jr * DD + kk * 32 + lg * 8);
            }
        }
        if (c + 1 < NCH) {
            STAGE(c + 1);
            asm volatile("s_waitcnt vmcnt(6)" ::: "memory");
        } else {
            asm volatile("s_waitcnt vmcnt(0)" ::: "memory");
        }
        __builtin_amdgcn_s_barrier();
        const char* Lb = &lds[c & 1][0][0];
        #pragma unroll
        for (int t = 0; t < 2; ++t) {
            f32x4 accc = {0.f, 0.f, 0.f, 0.f}, acci = {0.f, 0.f, 0.f, 0.f};
            #pragma unroll
            for (int kk = 0; kk < 4; ++kk) {
                accc = mfma_bf16(an[t][kk], bfrag[kk], accc);
                acci = mfma_bf16(ai[t][kk], bfrag[kk], acci);
            }
            int mo = lr * 512 + (wid * 32 + t * 16 + lg * 4) * 4;
            float4 y4 = *(const float4*)(Lb + mo);
            float4 n4 = *(const float4*)(Lb + 8192 + mo);
            int4   w4 = *(const int4*)(Lb + 16384 + mo);
            int j0 = j00 + c * JCH + wid * 32 + t * 16;
            float ya[4] = {y4.x, y4.y, y4.z, y4.w};
            float na[4] = {n4.x, n4.y, n4.z, n4.w};
            int   wa[4] = {w4.x, w4.y, w4.z, w4.w};
            #pragma unroll
            for (int r = 0; r < 4; ++r) {
                int J = j0 + lg * 4 + r;
                float y = ya[r];
                bool wm = (wa[r] != 0) || (R == J);
                float cross = accc[r] * 2.0f;
                float inter = acci[r] * 2.0f;
                if (wm && (y > 0.0f)) pos += y * cross;
                bool nm = (!wm) && (y == 0.0f);
                float nwc = fmaxf(na[r], 0.0f);
                float vc = nm ? nwc * cross : 0.0f;
                vc = (vc == 0.0f) ? SMALLV : vc;
                float vi = nm ? nwc * inter : 0.0f;
                vi = (vi == 0.0f) ? SMALLV : vi;
                s0 += exp2f(fmaf(vc, K1EXP, K2EXP)) + exp2f(fmaf(vi, K1EXP, K2EXP));
            }
        }
        asm volatile("s_waitcnt lgkmcnt(0)" ::: "memory");
        __builtin_amdgcn_s_barrier();
    }
    #pragma unroll
    for (int d = 16; d < 64; d <<= 1) s0 += __shfl_xor(s0, d);
    if (lg == 0) row_s[(size_t)R * FJS_TOT + js * 4 + wid] = s0;
    #pragma unroll
    for (int d = 1; d < 64; d <<= 1) pos += __shfl_xor(pos, d);
    if (lane == 0) lds_pos[wid] = pos;
    __syncthreads();
    if (threadIdx.x == 0)
        pos_part[blockIdx.x] = lds_pos[0] + lds_pos[1] + lds_pos[2] + lds_pos[3];
    #undef STAGE
}

__global__ __launch_bounds__(256) void lse_part_kernel(
    const float* __restrict__ row_s, float* __restrict__ lse_part)
{
    int R = blockIdx.x * 256 + threadIdx.x;
    float s = 0.0f;
    #pragma unroll
    for (int k = 0; k < FJS_TOT; ++k) s += row_s[(size_t)R * FJS_TOT + k];
    float v = 4.0f + __logf(s);
    #pragma unroll
    for (int d = 1; d < 64; d <<= 1) v += __shfl_xor(v, d);
    __shared__ float l[4];
    if ((threadIdx.x & 63) == 0) l[threadIdx.x >> 6] = v;
    __syncthreads();
    if (threadIdx.x == 0) lse_part[blockIdx.x] = l[0] + l[1] + l[2] + l[3];
}

__global__ __launch_bounds__(256) void final_kernel(
    const float* __restrict__ lse_part, const float* __restrict__ pos_part,
    const float* __restrict__ partials, float* __restrict__ out)
{
    int t = threadIdx.x;
    float lse = (t < 16) ? lse_part[t] : 0.0f;
    float pos = 0.0f;
    #pragma unroll
    for (int i = 0; i < 8; ++i) pos += pos_part[t + 256 * i];
    float xx = partials[t] + partials[t + 256];
    float yy = partials[512 + t];
    float xy = partials[768 + t];
    float pp = (t < 64) ? partials[1024 + t] : 0.0f;
    __shared__ float red[256];
    float vals[6] = {lse, pos, xx, yy, xy, pp};
    float tot[6];
    #pragma unroll
    for (int v = 0; v < 6; ++v) {
        red[t] = vals[v];
        __syncthreads();
        for (int d = 128; d > 0; d >>= 1) {
            if (t < d) red[t] += red[t + d];
            __syncthreads();
        }
        tot[v] = red[0];
        __syncthreads();
    }
    if (t == 0) {
        float feat = (tot[0] - tot[1]) / (float)NN;
        float sxx = tot[2] / ((float)NN * (NN - 1));
        float syy = tot[3] / ((float)MMR * (MMR - 1));
        float sxy = 2.0f * tot[4] / ((float)NN * MMR);
        out[0] = feat + sxx + syy - sxy + tot[5];
    }
}

// ---------------- RBF pair-sums, all four in one launch ----------------
__global__ __launch_bounds__(256) void rbf_all(
    const u16* __restrict__ real_bf, const u16* __restrict__ pseudo_bf,
    const u16* __restrict__ pseudos_bf,
    const float* __restrict__ nreal, const float* __restrict__ npseudo,
    const float* __restrict__ npseudos,
    float* __restrict__ partials)
{
    int b = blockIdx.x;
    const u16 *X, *Y; const float *nx, *ny;
    int js, cols, same, local;
    if (b < 512)       { X = real_bf;    Y = real_bf;    nx = nreal;    ny = nreal;    js = 16; cols = 256; same = 1; local = b; }
    else if (b < 768)  { X = pseudo_bf;  Y = pseudo_bf;  nx = npseudo;  ny = npseudo;  js = 16; cols = 128; same = 1; local = b - 512; }
    else if (b < 1024) { X = real_bf;    Y = pseudo_bf;  nx = nreal;    ny = npseudo;  js = 8;  cols = 256; same = 0; local = b - 768; }
    else               { X = pseudos_bf; Y = pseudos_bf; nx = npseudos; ny = npseudos; js = 8;  cols = 128; same = 1; local = b - 1024; }
    int jsx = local % js;
    int rb  = local / js;
    int wid = threadIdx.x >> 6;
    int lane = threadIdx.x & 63;
    int lr = lane & 15, lg = lane >> 4;
    int row0 = rb * 128 + wid * 32;
    const short* Xs = (const short*)X;
    const short* Ys = (const short*)Y;
    s16x8 a0[4], a1[4];
    #pragma unroll
    for (int kk = 0; kk < 4; ++kk) {
        a0[kk] = *(const s16x8*)(Xs + (size_t)(row0 + lr) * DD + kk * 32 + lg * 8);
        a1[kk] = *(const s16x8*)(Xs + (size_t)(row0 + 16 + lr) * DD + kk * 32 + lg * 8);
    }
    float nx0[4], nx1[4];
    #pragma unroll
    for (int r = 0; r < 4; ++r) {
        nx0[r] = nx[row0 + lg * 4 + r];
        nx1[r] = nx[row0 + 16 + lg * 4 + r];
    }
    float sum = 0.0f;
    int j0base = jsx * cols;
    for (int j0 = j0base; j0 < j0base + cols; j0 += 16) {
        int brow = j0 + lr;
        f32x4 c0 = {0.f, 0.f, 0.f, 0.f}, c1 = {0.f, 0.f, 0.f, 0.f};
        #pragma unroll
        for (int kk = 0; kk < 4; ++kk) {
            s16x8 bb = *(const s16x8*)(Ys + (size_t)brow * DD + kk * 32 + lg * 8);
            c0 = mfma_bf16(a0[kk], bb, c0);
            c1 = mfma_bf16(a1[kk], bb, c1);
        }
        int J = j0 + lr;
        float nyJ = ny[J];
        #pragma unroll
        for (int r = 0; r < 4; ++r) {
            int R0 = row0 + lg * 4 + r;
            float d0 = fmaxf(nx0[r] + nyJ - 2.0f * c0[r], 0.0f);
            if (!(same && (R0 == J))) sum += __expf(-d0 * 0.125f);
            int R1 = R0 + 16;
            float d1 = fmaxf(nx1[r] + nyJ - 2.0f * c1[r], 0.0f);
            if (!(same && (R1 == J))) sum += __expf(-d1 * 0.125f);
        }
    }
    #pragma unroll
    for (int d = 1; d < 64; d <<= 1) sum += __shfl_xor(sum, d);
    __shared__ float lds_s[4];
    if (lane == 0) lds_s[wid] = sum;
    __syncthreads();
    if (threadIdx.x == 0)
        partials[b] = lds_s[0] + lds_s[1] + lds_s[2] + lds_s[3];
}

extern "C" void kernel_launch(void* const* d_in, const int* in_sizes, int n_in,
                              void* d_out, int out_size, void* d_ws, size_t ws_size,
                              hipStream_t stream) {
    const float* zi      = (const float*)d_in[0];
    const float* z       = (const float*)d_in[1];
    const float* y_pse   = (const float*)d_in[2];
    const float* negw    = (const float*)d_in[3];
    const float* real    = (const float*)d_in[4];
    const float* pseudo  = (const float*)d_in[5];
    const float* pseudos = (const float*)d_in[6];
    const int*   w       = (const int*)d_in[7];
    float* out = (float*)d_out;

    char* ws = (char*)d_ws;
    u16* zin_bf     = (u16*)(ws + 0);                     // 1 MB
    u16* zn_bf      = (u16*)(ws + (1 << 20));             // 1 MB
    u16* real_bf    = (u16*)(ws + (2 << 20));             // 1 MB
    u16* pseudo_bf  = (u16*)(ws + (3 << 20));             // 512 KB
    u16* pseudos_bf = (u16*)(ws + (3 << 20) + (1 << 19)); // 256 KB
    float* nreal    = (float*)(ws + (15 << 18));          // 16 KB region
    float* npseudo  = nreal + NN;
    float* npseudos = npseudo + MMR;
    float*  partials  = (float*)(ws + (4 << 20));                 // 1088 f
    float*  lse_pv    = (float*)(ws + (4 << 20) + (8 << 10));     // 16 f
    float*  pos_part  = (float*)(ws + (4 << 20) + (16 << 10));    // 8192 f = 32 KB
    float*  srow_part = (float*)(ws + (4 << 20) + (64 << 10));    // 4096*16 f = 256 KB
    float*  row_s     = srow_part;                                // fallback reuse (exclusive)
    size_t gfull = (size_t)NN * NN * 2;   // bytes per full gram matrix (f16)
    size_t base = (size_t)5 << 20;

    int npass;
    if      (ws_size >= base + 2 * gfull)     npass = 1;
    else if (ws_size >= base + gfull)         npass = 2;
    else if (ws_size >= base + gfull / 2)     npass = 4;
    else                                      npass = 0;

    prep_all<<<3840, 256, 0, stream>>>(zi, z, real, pseudo, pseudos,
        zin_bf, zn_bf, real_bf, pseudo_bf, pseudos_bf, nreal, npseudo, npseudos);

    if (npass > 0) {
        int chunk = NN / npass;          // rows per pass
        int kmax = chunk / 512;          // marching iterations per pass
        u16* gc = (u16*)(ws + base);
        u16* gi = gc + (size_t)chunk * NN;
        for (int p = 0; p < npass; ++p) {
            int row0 = p * chunk;
            gram_kernel<<<2 * (chunk / 128) * 32, 256, 0, stream>>>(
                zin_bf, zn_bf, gc, gi, row0, chunk / 128);
            feat_stream<<<2048, 256, 0, stream>>>(
                y_pse, negw, w, gc, gi, row0, kmax, srow_part, pos_part, p);
        }
        rbf_all<<<1088, 256, 0, stream>>>(real_bf, pseudo_bf, pseudos_bf,
            nreal, npseudo, npseudos, partials);
        lse_stream_kernel<<<16, 256, 0, stream>>>(srow_part, lse_pv);
        final3_kernel<<<1, 256, 0, stream>>>(lse_pv, pos_part, npass * 8,
            partials, out);
    } else {
        feat_kernel<<<(NN / RB) * FJS, 256, 0, stream>>>(
            zin_bf, zn_bf, y_pse, negw, w, row_s, pos_part);
        rbf_all<<<1088, 256, 0, stream>>>(real_bf, pseudo_bf, pseudos_bf,
            nreal, npseudo, npseudos, partials);
        lse_part_kernel<<<16, 256, 0, stream>>>(row_s, lse_pv);
        final_kernel<<<1, 256, 0, stream>>>(lse_pv, pos_part, partials, out);
    }
}

// Round 11
// 93.554 us; speedup vs baseline: 1.6603x; 1.6603x over previous
//
#include <hip/hip_runtime.h>

#define NN 4096
#define DD 128
#define MMR 2048
#define KKE 1024
#define FJS 32
#define FCOLS (NN / FJS)      // 128
#define FTILES (FCOLS / 16)   // 8

typedef __attribute__((ext_vector_type(8))) short s16x8;
typedef __attribute__((ext_vector_type(4))) float f32x4;
typedef unsigned short u16;
typedef unsigned int u32;

// ln(1e-45) in fp32
#define SMALLV (-103.61632918439092f)
// exp(2*v - 4) == exp2(v*K1 + K2)
#define K1EXP 2.8853900817779268f
#define K2EXP (-5.7707801635558537f)

static __device__ __forceinline__ u16 f2bf(float x) {
    u32 u = __float_as_uint(x);
    u32 r = (u + 0x7fffu + ((u >> 16) & 1u)) >> 16;
    return (u16)r;
}

static __device__ __forceinline__ f32x4 mfma_bf16(s16x8 a, s16x8 b, f32x4 c) {
    return __builtin_amdgcn_mfma_f32_16x16x32_bf16(a, b, c, 0, 0, 0);
}

static __device__ __forceinline__ void gload_lds16(const void* g, void* l) {
    __builtin_amdgcn_global_load_lds(
        (const __attribute__((address_space(1))) void*)g,
        (__attribute__((address_space(3))) void*)l, 16, 0, 0);
}

// ---------------- prep (R3): zi/z swizzled bf16; real/pseudo/pseudos linear ----------------
// zi/z outputs written in XOR-swizzled chunk order: element d of row r lands
// at u16 index r*128 + (((d>>3)^(r&7))<<3) + (d&7) -> bank-conflict-reduced
// LDS tile reads after linear global_load_lds fill.
__global__ __launch_bounds__(256) void prep_all(
    const float* __restrict__ zi, const float* __restrict__ z,
    const float* __restrict__ real, const float* __restrict__ pseudo,
    const float* __restrict__ pseudos,
    u16* __restrict__ zin_bf, u16* __restrict__ zn_bf,
    u16* __restrict__ real_bf, u16* __restrict__ pseudo_bf,
    u16* __restrict__ pseudos_bf,
    float* __restrict__ nreal, float* __restrict__ npseudo,
    float* __restrict__ npseudos)
{
    int b = blockIdx.x;
    int sub = threadIdx.x >> 6, lane = threadIdx.x & 63;
    if (b < 2048) {
        int row = b * 4 + sub;   // 0..8191
        const float* src = (row < NN) ? zi : z;
        u16* dst = (row < NN) ? zin_bf : zn_bf;
        int r = (row < NN) ? row : row - NN;
        const float* p = src + (size_t)r * DD;
        float a = p[lane], c = p[lane + 64];
        float ss = a * a + c * c;
        #pragma unroll
        for (int d = 1; d < 64; d <<= 1) ss += __shfl_xor(ss, d);
        float nrm = fmaxf(sqrtf(ss), 1e-8f);
        int c0 = lane >> 3, b0 = lane & 7, rs = r & 7;
        dst[r * DD + ((c0 ^ rs) << 3) + b0]       = f2bf(a / nrm);
        dst[r * DD + (((8 + c0) ^ rs) << 3) + b0] = f2bf(c / nrm);
    } else {
        const float* src; u16* dst; float* sq; int r;
        if (b < 3072)      { r = (b - 2048) * 4 + sub; src = real;    dst = real_bf;    sq = nreal; }
        else if (b < 3584) { r = (b - 3072) * 4 + sub; src = pseudo;  dst = pseudo_bf;  sq = npseudo; }
        else               { r = (b - 3584) * 4 + sub; src = pseudos; dst = pseudos_bf; sq = npseudos; }
        const float* p = src + (size_t)r * DD;
        float a = p[lane], c = p[lane + 64];
        float ss = a * a + c * c;
        #pragma unroll
        for (int d = 1; d < 64; d <<= 1) ss += __shfl_xor(ss, d);
        if (lane == 0) sq[r] = ss;
        dst[r * DD + lane]      = f2bf(a);
        dst[r * DD + lane + 64] = f2bf(c);
    }
}

// ---------------- fused main: blocks [0,2048) = feat (R3 body);
//                  blocks [2048,3136) = RBF pair-sums ----------------
__global__ __launch_bounds__(256) void fused_kernel(
    const u16* __restrict__ zin, const u16* __restrict__ zn,
    const float* __restrict__ y_pse, const float* __restrict__ negw,
    const int* __restrict__ w,
    const u16* __restrict__ real_bf, const u16* __restrict__ pseudo_bf,
    const u16* __restrict__ pseudos_bf,
    const float* __restrict__ nreal, const float* __restrict__ npseudo,
    const float* __restrict__ npseudos,
    float* __restrict__ row_s, float* __restrict__ pos_part,
    float* __restrict__ partials)
{
    __shared__ char lds_t[2][8192];
    __shared__ float lds_red[4];
    int wid = threadIdx.x >> 6;
    int lane = threadIdx.x & 63;
    int lr = lane & 15, lg = lane >> 4;

    if (blockIdx.x < 2048) {
        // ================= feat body (R3, verbatim) =================
        int js = blockIdx.x % FJS;
        int rb = blockIdx.x / FJS;
        int sw = lr & 7;
        int row0 = rb * 64 + wid * 16;
        const char* zin_c = (const char*)zin;
        const char* zn_c  = (const char*)zn;

        int R = row0 + lr;
        s16x8 bfrag[4];
        #pragma unroll
        for (int kk = 0; kk < 4; ++kk)
            bfrag[kk] = *(const s16x8*)(zin_c + (size_t)R * 256 + (((kk * 4 + lg) ^ sw) << 4));

        int j0base = js * FCOLS;
        {
            const char* sA = zn_c  + (size_t)j0base * 256 + wid * 1024 + lane * 16;
            const char* sB = zin_c + (size_t)j0base * 256 + wid * 1024 + lane * 16;
            gload_lds16(sA, &lds_t[0][wid * 1024]);
            gload_lds16(sB, &lds_t[0][4096 + wid * 1024]);
        }
        asm volatile("" ::: "memory");

        const float4* yp  = (const float4*)(y_pse + (size_t)R * NN);
        const float4* npw = (const float4*)(negw  + (size_t)R * NN);
        const int4*   wp  = (const int4*)(w       + (size_t)R * NN);
        int qbase = (j0base >> 2) + lg;
        float4 y_cur = yp[qbase],  y_mid = yp[qbase + 4];
        float4 n_cur = npw[qbase], n_mid = npw[qbase + 4];
        int4   w_cur = wp[qbase],  w_mid = wp[qbase + 4];

        float s0 = 0.0f, pos = 0.0f;

        #pragma unroll
        for (int t = 0; t < FTILES; ++t) {
            if (t + 1 < FTILES) {
                int j1 = j0base + (t + 1) * 16;
                const char* sA = zn_c  + (size_t)j1 * 256 + wid * 1024 + lane * 16;
                const char* sB = zin_c + (size_t)j1 * 256 + wid * 1024 + lane * 16;
                gload_lds16(sA, &lds_t[(t + 1) & 1][wid * 1024]);
                gload_lds16(sB, &lds_t[(t + 1) & 1][4096 + wid * 1024]);
                // FIFO: [m(t)x3, s(t)x2 | m(t+1)x3, s(t+1)x2] -> drain oldest 5
                asm volatile("s_waitcnt vmcnt(5)" ::: "memory");
            } else {
                asm volatile("s_waitcnt vmcnt(0)" ::: "memory");
            }
            __builtin_amdgcn_s_barrier();

            const char* bp = &lds_t[t & 1][0];
            f32x4 accc = {0.f, 0.f, 0.f, 0.f}, acci = {0.f, 0.f, 0.f, 0.f};
            #pragma unroll
            for (int kk = 0; kk < 4; ++kk) {
                int off = lr * 256 + (((kk * 4 + lg) ^ sw) << 4);
                s16x8 an = *(const s16x8*)(bp + off);
                s16x8 ai = *(const s16x8*)(bp + 4096 + off);
                accc = mfma_bf16(an, bfrag[kk], accc);   // C[J,R] = z[J]·zi[R]
                acci = mfma_bf16(ai, bfrag[kk], acci);   // C[J,R] = zi[J]·zi[R]
            }
            int j0 = j0base + t * 16;
            float ya[4] = {y_cur.x, y_cur.y, y_cur.z, y_cur.w};
            float na[4] = {n_cur.x, n_cur.y, n_cur.z, n_cur.w};
            int   wa[4] = {w_cur.x, w_cur.y, w_cur.z, w_cur.w};
            #pragma unroll
            for (int r = 0; r < 4; ++r) {
                int J = j0 + lg * 4 + r;
                float y = ya[r];
                bool wm = (wa[r] != 0) || (R == J);
                float cross = accc[r] * 2.0f;   // cos / TEMP
                float inter = acci[r] * 2.0f;
                if (wm && (y > 0.0f)) pos += y * cross;
                bool nm = (!wm) && (y == 0.0f);
                float nwc = fmaxf(na[r], 0.0f);
                float vc = nm ? nwc * cross : 0.0f;
                vc = (vc == 0.0f) ? SMALLV : vc;
                float vi = nm ? nwc * inter : 0.0f;
                vi = (vi == 0.0f) ? SMALLV : vi;
                s0 += exp2f(fmaf(vc, K1EXP, K2EXP)) + exp2f(fmaf(vi, K1EXP, K2EXP));
            }
            float4 y_new = {0, 0, 0, 0}, n_new = {0, 0, 0, 0};
            int4 w_new = {0, 0, 0, 0};
            if (t + 2 < FTILES) {
                int q = qbase + (t + 2) * 4;
                y_new = yp[q]; n_new = npw[q]; w_new = wp[q];
            }
            y_cur = y_mid; y_mid = y_new;
            n_cur = n_mid; n_mid = n_new;
            w_cur = w_mid; w_mid = w_new;
            asm volatile("s_waitcnt lgkmcnt(0)" ::: "memory");
            __builtin_amdgcn_s_barrier();
        }

        #pragma unroll
        for (int d = 16; d < 64; d <<= 1) s0 += __shfl_xor(s0, d);
        if (lg == 0) row_s[(size_t)R * FJS + js] = s0;
        #pragma unroll
        for (int d = 1; d < 64; d <<= 1) pos += __shfl_xor(pos, d);
        if (lane == 0) lds_red[wid] = pos;
        __syncthreads();
        if (threadIdx.x == 0)
            pos_part[blockIdx.x] = lds_red[0] + lds_red[1] + lds_red[2] + lds_red[3];
    } else {
        // ================= RBF body =================
        int b = blockIdx.x - 2048;
        const u16 *X, *Y; const float *nx, *ny;
        int js, cols, same, local;
        if (b < 512)       { X = real_bf;    Y = real_bf;    nx = nreal;    ny = nreal;    js = 16; cols = 256; same = 1; local = b; }
        else if (b < 768)  { X = pseudo_bf;  Y = pseudo_bf;  nx = npseudo;  ny = npseudo;  js = 16; cols = 128; same = 1; local = b - 512; }
        else if (b < 1024) { X = real_bf;    Y = pseudo_bf;  nx = nreal;    ny = npseudo;  js = 8;  cols = 256; same = 0; local = b - 768; }
        else               { X = pseudos_bf; Y = pseudos_bf; nx = npseudos; ny = npseudos; js = 8;  cols = 128; same = 1; local = b - 1024; }
        int jsx = local % js;
        int rb  = local / js;
        int row0 = rb * 128 + wid * 32;
        const short* Xs = (const short*)X;
        const short* Ys = (const short*)Y;
        s16x8 a0[4], a1[4];
        #pragma unroll
        for (int kk = 0; kk < 4; ++kk) {
            a0[kk] = *(const s16x8*)(Xs + (size_t)(row0 + lr) * DD + kk * 32 + lg * 8);
            a1[kk] = *(const s16x8*)(Xs + (size_t)(row0 + 16 + lr) * DD + kk * 32 + lg * 8);
        }
        float nx0[4], nx1[4];
        #pragma unroll
        for (int r = 0; r < 4; ++r) {
            nx0[r] = nx[row0 + lg * 4 + r];
            nx1[r] = nx[row0 + 16 + lg * 4 + r];
        }
        float sum = 0.0f;
        int j0base = jsx * cols;
        for (int j0 = j0base; j0 < j0base + cols; j0 += 16) {
            int brow = j0 + lr;
            f32x4 c0 = {0.f, 0.f, 0.f, 0.f}, c1 = {0.f, 0.f, 0.f, 0.f};
            #pragma unroll
            for (int kk = 0; kk < 4; ++kk) {
                s16x8 bb = *(const s16x8*)(Ys + (size_t)brow * DD + kk * 32 + lg * 8);
                c0 = mfma_bf16(a0[kk], bb, c0);
                c1 = mfma_bf16(a1[kk], bb, c1);
            }
            int J = j0 + lr;
            float nyJ = ny[J];
            #pragma unroll
            for (int r = 0; r < 4; ++r) {
                int R0 = row0 + lg * 4 + r;
                float d0 = fmaxf(nx0[r] + nyJ - 2.0f * c0[r], 0.0f);
                if (!(same && (R0 == J))) sum += __expf(-d0 * 0.125f);
                int R1 = R0 + 16;
                float d1 = fmaxf(nx1[r] + nyJ - 2.0f * c1[r], 0.0f);
                if (!(same && (R1 == J))) sum += __expf(-d1 * 0.125f);
            }
        }
        #pragma unroll
        for (int d = 1; d < 64; d <<= 1) sum += __shfl_xor(sum, d);
        if (lane == 0) lds_red[wid] = sum;
        __syncthreads();
        if (threadIdx.x == 0)
            partials[b] = lds_red[0] + lds_red[1] + lds_red[2] + lds_red[3];
    }
}

// ---------------- per-row LSE finish ----------------
__global__ __launch_bounds__(256) void lse_part_kernel(
    const float* __restrict__ row_s, float* __restrict__ lse_part)
{
    int R = blockIdx.x * 256 + threadIdx.x;
    float s = 0.0f;
    #pragma unroll
    for (int k = 0; k < FJS; ++k) s += row_s[(size_t)R * FJS + k];
    float v = 4.0f + __logf(s);   // fixed-max LSE: max = 4
    #pragma unroll
    for (int d = 1; d < 64; d <<= 1) v += __shfl_xor(v, d);
    __shared__ float l[4];
    if ((threadIdx.x & 63) == 0) l[threadIdx.x >> 6] = v;
    __syncthreads();
    if (threadIdx.x == 0) lse_part[blockIdx.x] = l[0] + l[1] + l[2] + l[3];
}

// ---------------- final (1 block, deterministic) ----------------
__global__ __launch_bounds__(256) void final_kernel(
    const float* __restrict__ lse_part, const float* __restrict__ pos_part,
    const float* __restrict__ partials, float* __restrict__ out)
{
    int t = threadIdx.x;
    float lse = (t < 16) ? lse_part[t] : 0.0f;
    float pos = 0.0f;
    #pragma unroll
    for (int i = 0; i < 8; ++i) pos += pos_part[t + 256 * i];
    float xx = partials[t] + partials[t + 256];
    float yy = partials[512 + t];
    float xy = partials[768 + t];
    float pp = (t < 64) ? partials[1024 + t] : 0.0f;
    __shared__ float red[256];
    float vals[6] = {lse, pos, xx, yy, xy, pp};
    float tot[6];
    #pragma unroll
    for (int v = 0; v < 6; ++v) {
        red[t] = vals[v];
        __syncthreads();
        for (int d = 128; d > 0; d >>= 1) {
            if (t < d) red[t] += red[t + d];
            __syncthreads();
        }
        tot[v] = red[0];
        __syncthreads();
    }
    if (t == 0) {
        float feat = (tot[0] - tot[1]) / (float)NN;
        float sxx = tot[2] / ((float)NN * (NN - 1));
        float syy = tot[3] / ((float)MMR * (MMR - 1));
        float sxy = 2.0f * tot[4] / ((float)NN * MMR);
        out[0] = feat + sxx + syy - sxy + tot[5];
    }
}

extern "C" void kernel_launch(void* const* d_in, const int* in_sizes, int n_in,
                              void* d_out, int out_size, void* d_ws, size_t ws_size,
                              hipStream_t stream) {
    const float* zi      = (const float*)d_in[0];
    const float* z       = (const float*)d_in[1];
    const float* y_pse   = (const float*)d_in[2];
    const float* negw    = (const float*)d_in[3];
    const float* real    = (const float*)d_in[4];
    const float* pseudo  = (const float*)d_in[5];
    const float* pseudos = (const float*)d_in[6];
    const int*   w       = (const int*)d_in[7];
    float* out = (float*)d_out;

    char* ws = (char*)d_ws;
    u16* zin_bf     = (u16*)(ws + 0);                     // 1 MB (swizzled)
    u16* zn_bf      = (u16*)(ws + (1 << 20));             // 1 MB (swizzled)
    u16* real_bf    = (u16*)(ws + (2 << 20));             // 1 MB
    u16* pseudo_bf  = (u16*)(ws + (3 << 20));             // 512 KB
    u16* pseudos_bf = (u16*)(ws + (3 << 20) + (1 << 19)); // 256 KB
    float* nreal    = (float*)(ws + (15 << 18));          // 16 KB region
    float* npseudo  = nreal + NN;
    float* npseudos = npseudo + MMR;
    float* row_s    = (float*)(ws + (4 << 20));           // 4096*32 f = 512 KB
    float* pos_part = (float*)(ws + (4 << 20) + (1 << 19)); // 2048 f
    float* partials = pos_part + 2048;                      // 1088 f
    float* lse_pv   = partials + 1088;                      // 16 f

    prep_all<<<3840, 256, 0, stream>>>(zi, z, real, pseudo, pseudos,
        zin_bf, zn_bf, real_bf, pseudo_bf, pseudos_bf, nreal, npseudo, npseudos);

    fused_kernel<<<2048 + 1088, 256, 0, stream>>>(
        zin_bf, zn_bf, y_pse, negw, w,
        real_bf, pseudo_bf, pseudos_bf, nreal, npseudo, npseudos,
        row_s, pos_part, partials);

    lse_part_kernel<<<16, 256, 0, stream>>>(row_s, lse_pv);

    final_kernel<<<1, 256, 0, stream>>>(lse_pv, pos_part, partials, out);
}